// Round 3
// baseline (70.974 us; speedup 1.0000x reference)
//
#include <hip/hip_runtime.h>
#include <hip/hip_bf16.h>

#define M_DIM 4096
#define N_DIM 8192
#define D_DIM 256
#define BM 128
#define BN 128
#define BK 64                        /* K-step: 4 steps over D=256 */
#define HALF_BYTES (BM * BK * 2)     /* 16 KiB: one tile (A or B), 128 B rows */
#define BUF_BYTES  (2 * HALF_BYTES)  /* 32 KiB: A+B for one K-step */

typedef __attribute__((ext_vector_type(8))) short short8; // 8 bf16 = 4 VGPR
typedef __attribute__((ext_vector_type(4))) float f32x4;  // MFMA C/D frag

__device__ inline unsigned short f2bf(float f) {
    __hip_bfloat16 h = __float2bfloat16(f);
    return *reinterpret_cast<unsigned short*>(&h);
}

// ---------------------------------------------------------------------------
// prep: fp32 -> bf16 rows for X and X_train, per-row sum-of-squares, zero out.
// One wave per row (64 lanes x float4 = 256 elems).
// ---------------------------------------------------------------------------
__global__ __launch_bounds__(256) void prep_kernel(
    const float* __restrict__ X, const float* __restrict__ T,
    unsigned short* __restrict__ Xb, unsigned short* __restrict__ Tb,
    float* __restrict__ sq1, float* __restrict__ sq2,
    float* __restrict__ out)
{
    const int gid = blockIdx.x * 256 + threadIdx.x;
    if (gid < M_DIM) out[gid] = 0.0f;            // zero the output accumulator

    const int row  = blockIdx.x * 4 + (threadIdx.x >> 6);
    const int lane = threadIdx.x & 63;
    const float* src; unsigned short* dst; float* sqp; int r;
    if (row < M_DIM) { src = X; dst = Xb; sqp = sq1; r = row; }
    else             { src = T; dst = Tb; sqp = sq2; r = row - M_DIM; }

    const float4* s4 = reinterpret_cast<const float4*>(src + (size_t)r * D_DIM);
    float4 v = s4[lane];
    float ss = v.x * v.x + v.y * v.y + v.z * v.z + v.w * v.w;

    ushort4 b4;
    b4.x = f2bf(v.x); b4.y = f2bf(v.y); b4.z = f2bf(v.z); b4.w = f2bf(v.w);
    reinterpret_cast<ushort4*>(dst + (size_t)r * D_DIM)[lane] = b4;

    #pragma unroll
    for (int o = 1; o < 64; o <<= 1) ss += __shfl_xor(ss, o);
    if (lane == 0) sqp[r] = ss;
}

// ---------------------------------------------------------------------------
// Fused RBF GEMM: 128x128 tile, 8 waves (2x4 wave grid, 64x32 out each),
// BK=64 K-loop fully unrolled, DOUBLE-BUFFERED LDS (2 x 32 KiB) with
// prefetch-before-compute (T3-lite): stage(t+1) issued before ds_read/MFMA
// of step t, one barrier per step -> load latency hides under MFMA.
// 16 waves/CU at 2 blocks/CU (vs 7.5 in round 2).
// LDS rows 128 B; 16 B slots XOR-swizzled by row&7 on both global source
// and ds_read address (G21 involution) -> 0 bank conflicts (verified R2).
// ---------------------------------------------------------------------------
__global__ __launch_bounds__(512) void gemm_kernel(
    const unsigned short* __restrict__ Xb, const unsigned short* __restrict__ Tb,
    const float* __restrict__ sq1, const float* __restrict__ sq2,
    const float* __restrict__ alpha, float* __restrict__ out)
{
    __shared__ __align__(16) char smem[2 * BUF_BYTES]; // 64 KiB
    const int bm   = blockIdx.x & 31;   // bm fastest: per-XCD A set L2-resident
    const int bn   = blockIdx.x >> 5;
    const int tid  = threadIdx.x;
    const int wid  = tid >> 6;          // wave 0..7
    const int lane = tid & 63;

    const char* gA = (const char*)(Xb + (size_t)bm * BM * D_DIM);
    const char* gB = (const char*)(Tb + (size_t)bn * BN * D_DIM);

    // Staging: per K-step each tile = 16 chunks of 1 KiB (8 rows x 128 B);
    // 8 waves -> 2 A-chunks + 2 B-chunks per wave. Lane l: row-in-chunk
    // rsub=l>>3, slot=l&7; source slot pre-swizzled: slot^rsub (involution).
    const int rsub = lane >> 3;
    const int sg16 = ((lane & 7) ^ rsub) * 16;

    const int wr  = wid >> 2, wc = wid & 3;  // 2x4 waves, 64x32 out each
    const int l15 = lane & 15;
    const int lg  = lane >> 4;
    const int xr  = l15 & 7;                 // row&7 for this lane's frag rows

    f32x4 acc[4][2];
    #pragma unroll
    for (int m = 0; m < 4; ++m)
        #pragma unroll
        for (int n = 0; n < 2; ++n) acc[m][n] = (f32x4)0.0f;

    int abase[4], bbase[2];
    #pragma unroll
    for (int m = 0; m < 4; ++m) abase[m] = (wr * 64 + m * 16 + l15) * 128;
    #pragma unroll
    for (int n = 0; n < 2; ++n) bbase[n] = HALF_BYTES + (wc * 32 + n * 16 + l15) * 128;

    // stage K-step kt into buffer b (A at b*BUF, B at b*BUF+HALF)
    auto stage = [&](int b, int kt) {
        const int ktb = kt * (BK * 2);           // k-window byte offset in row
        #pragma unroll
        for (int c = 0; c < 2; ++c) {
            const int chunk = wid * 2 + c;       // 0..15
            const int ob = b * BUF_BYTES + chunk * 1024;   // wave-uniform
            const size_t so = (size_t)(chunk * 8 + rsub) * (D_DIM * 2) + ktb + sg16;
            __builtin_amdgcn_global_load_lds(
                (const __attribute__((address_space(1))) void*)(gA + so),
                (__attribute__((address_space(3))) void*)(smem + ob), 16, 0, 0);
            __builtin_amdgcn_global_load_lds(
                (const __attribute__((address_space(1))) void*)(gB + so),
                (__attribute__((address_space(3))) void*)(smem + ob + HALF_BYTES), 16, 0, 0);
        }
    };

    stage(0, 0);
    __syncthreads();                  // buf0 ready

    #pragma unroll
    for (int kt = 0; kt < D_DIM / BK; ++kt) {
        const int cur = kt & 1;
        if (kt < D_DIM / BK - 1) stage(cur ^ 1, kt + 1);  // prefetch in flight
        const int boff = cur * BUF_BYTES;
        #pragma unroll
        for (int kk = 0; kk < 2; ++kk) {
            const int ko = (((kk << 2) + lg) ^ xr) << 4;  // swizzled slot byte
            short8 af[4], bf[2];
            #pragma unroll
            for (int m = 0; m < 4; ++m)
                af[m] = *(const short8*)(smem + boff + abase[m] + ko);
            #pragma unroll
            for (int n = 0; n < 2; ++n)
                bf[n] = *(const short8*)(smem + boff + bbase[n] + ko);
            #pragma unroll
            for (int m = 0; m < 4; ++m)
                #pragma unroll
                for (int n = 0; n < 2; ++n)
                    acc[m][n] = __builtin_amdgcn_mfma_f32_16x16x32_bf16(
                        af[m], bf[n], acc[m][n], 0, 0, 0);
        }
        __syncthreads();  // drains prefetch vmcnt; next buffer ready
    }

    // Epilogue: C/D layout col=lane&15, row=(lane>>4)*4+reg (m89-verified).
    const int brow = bm * BM, bcol = bn * BN + wc * 32;
    float sq2c[2], alf[2];
    #pragma unroll
    for (int n = 0; n < 2; ++n) {
        const int gj = bcol + n * 16 + l15;
        sq2c[n] = sq2[gj];
        alf[n]  = alpha[gj];
    }
    #pragma unroll
    for (int m = 0; m < 4; ++m) {
        #pragma unroll
        for (int r = 0; r < 4; ++r) {
            const int gi = brow + wr * 64 + m * 16 + lg * 4 + r;
            const float s1 = sq1[gi];
            float p = 0.0f;
            #pragma unroll
            for (int n = 0; n < 2; ++n) {
                const float d = s1 + sq2c[n] - 2.0f * acc[m][n][r];
                p += __expf(-0.5f * d) * alf[n];
            }
            // reduce over the 16 lanes (l15) holding this row's 32 columns
            p += __shfl_xor(p, 1);
            p += __shfl_xor(p, 2);
            p += __shfl_xor(p, 4);
            p += __shfl_xor(p, 8);
            if (l15 == 0) atomicAdd(&out[gi], p);
        }
    }
}

extern "C" void kernel_launch(void* const* d_in, const int* in_sizes, int n_in,
                              void* d_out, int out_size, void* d_ws, size_t ws_size,
                              hipStream_t stream)
{
    const float* X  = (const float*)d_in[0];
    const float* T  = (const float*)d_in[1];
    const float* al = (const float*)d_in[2];
    float* out = (float*)d_out;

    char* ws = (char*)d_ws;
    unsigned short* Xb = (unsigned short*)ws;                               // 2 MiB
    unsigned short* Tb = (unsigned short*)(ws + (size_t)M_DIM * D_DIM * 2); // 4 MiB
    float* sq1 = (float*)(ws + (size_t)(M_DIM + N_DIM) * D_DIM * 2);        // 16 KiB
    float* sq2 = sq1 + M_DIM;                                               // 32 KiB

    prep_kernel<<<(M_DIM + N_DIM) / 4, 256, 0, stream>>>(X, T, Xb, Tb, sq1, sq2, out);
    gemm_kernel<<<(M_DIM / BM) * (N_DIM / BN), 512, 0, stream>>>(Xb, Tb, sq1, sq2, al, out);
}

// Round 4
// 46.470 us; speedup vs baseline: 1.5273x; 1.5273x over previous
//
#include <hip/hip_runtime.h>
#include <hip/hip_bf16.h>

#define M_DIM 4096
#define N_DIM 8192
#define D_DIM 256
#define BM 256
#define BN 256
#define BK 64                        /* K-step: 4 steps over D=256 */
#define NKT (D_DIM / BK)
#define HALF_BYTES (BM * BK * 2)     /* 32 KiB: one tile (A or B) per step */
#define BUF_BYTES  (2 * HALF_BYTES)  /* 64 KiB: A+B for one K-step */
#define C_EXP (-0.7213475204444817f) /* -1/(2 ln2): exp(-d/2) = 2^(d*C_EXP) */
#define K_ACC (1.4426950408889634f)  /* -2*C_EXP: acc coefficient */

typedef __attribute__((ext_vector_type(8))) short short8; // 8 bf16 = 4 VGPR
typedef __attribute__((ext_vector_type(4))) float f32x4;  // MFMA C/D frag

__device__ inline unsigned short f2bf(float f) {
    __hip_bfloat16 h = __float2bfloat16(f);
    return *reinterpret_cast<unsigned short*>(&h);
}

// ---------------------------------------------------------------------------
// prep: fp32 -> bf16 rows for X and X_train; per-row sum-of-squares PRE-SCALED
// by -1/(2 ln2) so the epilogue is a single fma + exp2 per term.
// One wave per row (64 lanes x float4 = 256 elems).
// ---------------------------------------------------------------------------
__global__ __launch_bounds__(256) void prep_kernel(
    const float* __restrict__ X, const float* __restrict__ T,
    unsigned short* __restrict__ Xb, unsigned short* __restrict__ Tb,
    float* __restrict__ sq1, float* __restrict__ sq2)
{
    const int row  = blockIdx.x * 4 + (threadIdx.x >> 6);
    const int lane = threadIdx.x & 63;
    const float* src; unsigned short* dst; float* sqp; int r;
    if (row < M_DIM) { src = X; dst = Xb; sqp = sq1; r = row; }
    else             { src = T; dst = Tb; sqp = sq2; r = row - M_DIM; }

    const float4* s4 = reinterpret_cast<const float4*>(src + (size_t)r * D_DIM);
    float4 v = s4[lane];
    float ss = v.x * v.x + v.y * v.y + v.z * v.z + v.w * v.w;

    ushort4 b4;
    b4.x = f2bf(v.x); b4.y = f2bf(v.y); b4.z = f2bf(v.z); b4.w = f2bf(v.w);
    reinterpret_cast<ushort4*>(dst + (size_t)r * D_DIM)[lane] = b4;

    #pragma unroll
    for (int o = 1; o < 64; o <<= 1) ss += __shfl_xor(ss, o);
    if (lane == 0) sqp[r] = ss * C_EXP;
}

// ---------------------------------------------------------------------------
// Fused RBF GEMM, 256x256 tile (m201 geometry): 8 waves (2x4), wave tile
// 128x64 (acc[8][4]), BK=64 K-loop unrolled, double-buffered 128 KiB LDS,
// prefetch-before-compute. NO ATOMICS: intra-block LDS reduction -> one
// coalesced store per row into part[bn][row]; reduce_kernel sums the 32
// bn-partials. LDS rows 128 B, 16 B slots XOR-swizzled by row&7 on both
// sides (G21; 0 conflicts measured R2/R3).
// ---------------------------------------------------------------------------
__global__ __launch_bounds__(512, 2) void gemm_kernel(
    const unsigned short* __restrict__ Xb, const unsigned short* __restrict__ Tb,
    const float* __restrict__ sq1, const float* __restrict__ sq2,
    const float* __restrict__ alpha, float* __restrict__ part)
{
    __shared__ __align__(16) char smem[2 * BUF_BYTES]; // 128 KiB
    const int bm   = blockIdx.x & 15;   // bm fastest: XCD x sees bm in {x,x+8}
    const int bn   = blockIdx.x >> 4;   // -> per-XCD A set = 256 KB, L2-resident
    const int tid  = threadIdx.x;
    const int wid  = tid >> 6;          // wave 0..7
    const int lane = tid & 63;

    const char* gA = (const char*)Xb + (size_t)bm * BM * (D_DIM * 2);
    const char* gB = (const char*)Tb + (size_t)bn * BN * (D_DIM * 2);

    // Staging: per step each tile = 32 chunks of 1 KiB (8 rows x 128 B);
    // 8 waves -> 4 A-chunks + 4 B-chunks per wave. Lane l: row-in-chunk
    // rsub=l>>3, slot=l&7; source slot pre-swizzled slot^rsub (involution).
    const int rsub = lane >> 3;
    const int sg16 = ((lane & 7) ^ rsub) * 16;

    const int wr  = wid >> 2, wc = wid & 3;  // 2x4 waves, 128x64 out each
    const int l15 = lane & 15;
    const int lg  = lane >> 4;
    const int xr  = l15 & 7;                 // row&7 for this lane's frag rows

    f32x4 acc[8][4];
    #pragma unroll
    for (int m = 0; m < 8; ++m)
        #pragma unroll
        for (int n = 0; n < 4; ++n) acc[m][n] = (f32x4)0.0f;

    int abase[8], bbase[4];
    #pragma unroll
    for (int m = 0; m < 8; ++m) abase[m] = (wr * 128 + m * 16 + l15) * 128;
    #pragma unroll
    for (int n = 0; n < 4; ++n) bbase[n] = HALF_BYTES + (wc * 64 + n * 16 + l15) * 128;

    auto stage = [&](int b, int kt) {
        const int ktb = kt * (BK * 2);           // k-window byte offset in row
        #pragma unroll
        for (int c = 0; c < 4; ++c) {
            const int chunk = wid * 4 + c;       // 0..31
            const int ob = b * BUF_BYTES + chunk * 1024;   // wave-uniform
            const size_t so = (size_t)(chunk * 8 + rsub) * (D_DIM * 2) + ktb + sg16;
            __builtin_amdgcn_global_load_lds(
                (const __attribute__((address_space(1))) void*)(gA + so),
                (__attribute__((address_space(3))) void*)(smem + ob), 16, 0, 0);
            __builtin_amdgcn_global_load_lds(
                (const __attribute__((address_space(1))) void*)(gB + so),
                (__attribute__((address_space(3))) void*)(smem + ob + HALF_BYTES), 16, 0, 0);
        }
    };

    stage(0, 0);
    __syncthreads();                  // buf0 ready

    #pragma unroll
    for (int kt = 0; kt < NKT; ++kt) {
        const int cur = kt & 1;
        if (kt < NKT - 1) stage(cur ^ 1, kt + 1);  // prefetch in flight
        const int boff = cur * BUF_BYTES;
        #pragma unroll
        for (int kk = 0; kk < 2; ++kk) {
            const int ko = (((kk << 2) + lg) ^ xr) << 4;  // swizzled slot byte
            short8 af[8], bf[4];
            #pragma unroll
            for (int m = 0; m < 8; ++m)
                af[m] = *(const short8*)(smem + boff + abase[m] + ko);
            #pragma unroll
            for (int n = 0; n < 4; ++n)
                bf[n] = *(const short8*)(smem + boff + bbase[n] + ko);
            #pragma unroll
            for (int m = 0; m < 8; ++m)
                #pragma unroll
                for (int n = 0; n < 4; ++n)
                    acc[m][n] = __builtin_amdgcn_mfma_f32_16x16x32_bf16(
                        af[m], bf[n], acc[m][n], 0, 0, 0);
        }
        __syncthreads();  // drains prefetch vmcnt; next buffer ready
    }

    // ---- Epilogue: exp2 + alpha-weighted row reduce, NO atomics ----
    // C/D layout col=lane&15, row=(lane>>4)*4+reg (m89-verified).
    float s2c[4], alf[4];
    #pragma unroll
    for (int n = 0; n < 4; ++n) {
        const int gj = bn * BN + wc * 64 + n * 16 + l15;
        s2c[n] = sq2[gj];      // pre-scaled by C_EXP
        alf[n] = alpha[gj];
    }
    float* red = (float*)smem;            // 4 KB, buffers dead after K-loop
    #pragma unroll
    for (int m = 0; m < 8; ++m) {
        #pragma unroll
        for (int r = 0; r < 4; ++r) {
            const int lrow = wr * 128 + m * 16 + lg * 4 + r; // block-local row
            const float s1v = sq1[bm * BM + lrow];           // pre-scaled
            float p = 0.0f;
            #pragma unroll
            for (int n = 0; n < 4; ++n) {
                // arg = (sq1 + sq2 - 2*dot) * C_EXP  (always <= ~-180: exp2->0)
                const float arg = fmaf(acc[m][n][r], K_ACC, s1v + s2c[n]);
                p = fmaf(__builtin_amdgcn_exp2f(arg), alf[n], p);
            }
            // reduce over the 16 l15-lanes holding this row's 64 columns
            p += __shfl_xor(p, 1);
            p += __shfl_xor(p, 2);
            p += __shfl_xor(p, 4);
            p += __shfl_xor(p, 8);
            if (l15 == 0) red[wc * 256 + lrow] = p;
        }
    }
    __syncthreads();
    if (tid < 256) {
        const float s = red[tid] + red[256 + tid] + red[512 + tid] + red[768 + tid];
        part[(size_t)bn * M_DIM + bm * BM + tid] = s;   // coalesced, contention-free
    }
}

// ---------------------------------------------------------------------------
// reduce: out[i] = sum over 32 bn-slices of part[bn][i]. 16 blocks x 256.
// ---------------------------------------------------------------------------
__global__ __launch_bounds__(256) void reduce_kernel(
    const float* __restrict__ part, float* __restrict__ out)
{
    const int gi = blockIdx.x * 256 + threadIdx.x;
    float s = 0.0f;
    #pragma unroll
    for (int b = 0; b < N_DIM / BN; ++b) s += part[(size_t)b * M_DIM + gi];
    out[gi] = s;
}

extern "C" void kernel_launch(void* const* d_in, const int* in_sizes, int n_in,
                              void* d_out, int out_size, void* d_ws, size_t ws_size,
                              hipStream_t stream)
{
    const float* X  = (const float*)d_in[0];
    const float* T  = (const float*)d_in[1];
    const float* al = (const float*)d_in[2];
    float* out = (float*)d_out;

    char* ws = (char*)d_ws;
    unsigned short* Xb = (unsigned short*)ws;                               // 2 MiB
    unsigned short* Tb = (unsigned short*)(ws + (size_t)M_DIM * D_DIM * 2); // 4 MiB
    float* sq1 = (float*)(ws + (size_t)(M_DIM + N_DIM) * D_DIM * 2);        // 16 KiB
    float* sq2 = sq1 + M_DIM;                                               // 32 KiB
    float* part = sq2 + N_DIM;                                              // 512 KiB

    prep_kernel<<<(M_DIM + N_DIM) / 4, 256, 0, stream>>>(X, T, Xb, Tb, sq1, sq2);
    gemm_kernel<<<(M_DIM / BM) * (N_DIM / BN), 512, 0, stream>>>(Xb, Tb, sq1, sq2, al, part);
    reduce_kernel<<<M_DIM / 256, 256, 0, stream>>>(part, out);
}